// Round 1
// baseline (590.590 us; speedup 1.0000x reference)
//
#include <hip/hip_runtime.h>

// EdgeBlock: out = relu(concat(node[snd], node[rcv], edge) @ w1 + b1) @ w2 + b2
// E=800000, N_NODES=50000, D=128. fp32 in/out, fp16 MFMA compute.

#define NE 800000
#define DD 128

typedef float f32x4v __attribute__((ext_vector_type(4)));
typedef float f32x16 __attribute__((ext_vector_type(16)));
typedef _Float16 f16x8 __attribute__((ext_vector_type(8)));

__device__ __forceinline__ f16x8 cvt8(f32x4v lo, f32x4v hi) {
    f16x8 r;
    r[0] = (_Float16)lo[0]; r[1] = (_Float16)lo[1];
    r[2] = (_Float16)lo[2]; r[3] = (_Float16)lo[3];
    r[4] = (_Float16)hi[0]; r[5] = (_Float16)hi[1];
    r[6] = (_Float16)hi[2]; r[7] = (_Float16)hi[3];
    return r;
}

// Transpose + downcast weights: w1[384][128] -> w1t[128][384] fp16, w2[128][128] -> w2t[128][128] fp16
__global__ void prep_w(const float* __restrict__ w1, const float* __restrict__ w2,
                       _Float16* __restrict__ w1t, _Float16* __restrict__ w2t) {
    int i = blockIdx.x * 256 + threadIdx.x;
    if (i < 384 * 128) {
        int n = i / 384;
        int k = i - n * 384;
        w1t[i] = (_Float16)w1[(size_t)k * 128 + n];
    } else {
        int j = i - 384 * 128;
        int n = j >> 7;
        int k = j & 127;
        w2t[j] = (_Float16)w2[(size_t)k * 128 + n];
    }
}

__global__ __launch_bounds__(256) void edge_mlp(
    const float* __restrict__ node_attr,
    const int* __restrict__ eidx,
    const float* __restrict__ edge_attr,
    const _Float16* __restrict__ w1t,
    const float* __restrict__ b1,
    const _Float16* __restrict__ w2t,
    const float* __restrict__ b2,
    float* __restrict__ out) {
    // per-wave h buffer: 32 rows x 128 cols fp16 = 8KB, x4 waves = 32KB
    __shared__ _Float16 hbuf[4][32 * 128];

    const int tid = threadIdx.x;
    const int wid = tid >> 6;
    const int lane = tid & 63;
    const int r31 = lane & 31;   // MFMA row/col within 32
    const int g2 = lane >> 5;    // k-half selector
    const int ebase = blockIdx.x * 128 + wid * 32;
    const int e = ebase + r31;   // this lane's edge row

    const int snd = eidx[e];
    const int rcv = eidx[NE + e];

    const float* baseS = node_attr + (size_t)snd * DD;
    const float* baseR = node_attr + (size_t)rcv * DD;
    const float* baseE = edge_attr + (size_t)e * DD;

    // ---------------- GEMM1: [32 x 384] @ [384 x 128] ----------------
    f32x16 acc[4] = {};  // 4 N-fragments of 32 cols each

    #pragma unroll
    for (int seg = 0; seg < 3; seg++) {
        const float* bp = (seg == 0) ? baseS : (seg == 1) ? baseR : baseE;
        #pragma unroll
        for (int kk8 = 0; kk8 < 8; kk8++) {
            const int kk = seg * 8 + kk8;           // global K-step 0..23
            const float* p = bp + kk8 * 16 + g2 * 8;
            f32x4v lo = *(const f32x4v*)p;
            f32x4v hi = *(const f32x4v*)(p + 4);
            f16x8 a = cvt8(lo, hi);
            #pragma unroll
            for (int n = 0; n < 4; n++) {
                // B: w1t[col][k], col = n*32 + r31, k = kk*16 + g2*8 .. +7
                f16x8 b = *(const f16x8*)(w1t + (size_t)(n * 32 + r31) * 384 + kk * 16 + g2 * 8);
                acc[n] = __builtin_amdgcn_mfma_f32_32x32x16_f16(a, b, acc[n], 0, 0, 0);
            }
        }
    }

    // bias + relu, write h to LDS (fp16) with XOR swizzle
    float b1v[4];
    #pragma unroll
    for (int n = 0; n < 4; n++) b1v[n] = b1[n * 32 + r31];

    char* hw = (char*)&hbuf[wid][0];
    #pragma unroll
    for (int n = 0; n < 4; n++) {
        const int col = n * 32 + r31;
        #pragma unroll
        for (int reg = 0; reg < 16; reg++) {
            // D layout (32x32): col = lane&31, row = (reg&3) + 8*(reg>>2) + 4*(lane>>5)
            const int row = (reg & 3) + 8 * (reg >> 2) + 4 * g2;
            float v = acc[n][reg] + b1v[n];
            v = fmaxf(v, 0.0f);
            const int byteoff = row * 256 + ((col * 2) ^ ((row & 7) << 4));
            *(_Float16*)(hw + byteoff) = (_Float16)v;
        }
    }

    __syncthreads();

    // ---------------- GEMM2: [32 x 128] @ [128 x 128] ----------------
    f32x16 acc2[4] = {};
    #pragma unroll
    for (int kk = 0; kk < 8; kk++) {
        const int row = r31;
        const int kbyte = (kk * 16 + g2 * 8) * 2;
        f16x8 a = *(const f16x8*)(hw + row * 256 + (kbyte ^ ((row & 7) << 4)));
        #pragma unroll
        for (int n = 0; n < 4; n++) {
            f16x8 b = *(const f16x8*)(w2t + (size_t)(n * 32 + r31) * 128 + kk * 16 + g2 * 8);
            acc2[n] = __builtin_amdgcn_mfma_f32_32x32x16_f16(a, b, acc2[n], 0, 0, 0);
        }
    }

    // bias + store fp32
    float b2v[4];
    #pragma unroll
    for (int n = 0; n < 4; n++) b2v[n] = b2[n * 32 + r31];

    #pragma unroll
    for (int n = 0; n < 4; n++) {
        #pragma unroll
        for (int reg = 0; reg < 16; reg++) {
            const int row = (reg & 3) + 8 * (reg >> 2) + 4 * g2;
            out[(size_t)(ebase + row) * DD + n * 32 + r31] = acc2[n][reg] + b2v[n];
        }
    }
}

extern "C" void kernel_launch(void* const* d_in, const int* in_sizes, int n_in,
                              void* d_out, int out_size, void* d_ws, size_t ws_size,
                              hipStream_t stream) {
    const float* node_attr = (const float*)d_in[0];
    const int* eidx = (const int*)d_in[1];
    const float* edge_attr = (const float*)d_in[2];
    const float* w1 = (const float*)d_in[3];
    const float* b1 = (const float*)d_in[4];
    const float* w2 = (const float*)d_in[5];
    const float* b2 = (const float*)d_in[6];
    float* out = (float*)d_out;

    _Float16* w1t = (_Float16*)d_ws;            // 128*384 fp16 = 96KB
    _Float16* w2t = w1t + 384 * 128;            // 128*128 fp16 = 32KB

    prep_w<<<256, 256, 0, stream>>>(w1, w2, w1t, w2t);
    edge_mlp<<<6250, 256, 0, stream>>>(node_attr, eidx, edge_attr, w1t, b1, w2t, b2, out);
}

// Round 2
// 399.113 us; speedup vs baseline: 1.4798x; 1.4798x over previous
//
#include <hip/hip_runtime.h>

// EdgeBlock: out = relu(concat(node[snd], node[rcv], edge) @ w1 + b1) @ w2 + b2
// E=800000, N_NODES=50000, D=128. fp32 in/out, fp16 MFMA compute.
// w1^T fp16 pre-swizzled in ws -> staged to LDS per block; B-frags via ds_read_b128.

#define NE 800000
#define DD 128

typedef float f32x4v __attribute__((ext_vector_type(4)));
typedef float f32x16 __attribute__((ext_vector_type(16)));
typedef _Float16 f16x8 __attribute__((ext_vector_type(8)));

__device__ __forceinline__ f16x8 cvt8(f32x4v lo, f32x4v hi) {
    f16x8 r;
    r[0] = (_Float16)lo[0]; r[1] = (_Float16)lo[1];
    r[2] = (_Float16)lo[2]; r[3] = (_Float16)lo[3];
    r[4] = (_Float16)hi[0]; r[5] = (_Float16)hi[1];
    r[6] = (_Float16)hi[2]; r[7] = (_Float16)hi[3];
    return r;
}

// w1[384][128] -> w1t_swz: fp16, layout col*768B + ((k*2) ^ ((col&7)<<4))
// w2[128][128] -> w2t: fp16 [col][k] linear
__global__ void prep_w(const float* __restrict__ w1, const float* __restrict__ w2,
                       _Float16* __restrict__ w1t, _Float16* __restrict__ w2t) {
    int i = blockIdx.x * 256 + threadIdx.x;   // 65536 total
    if (i < 384 * 128) {
        int col = i / 384;
        int k = i - col * 384;
        float v = w1[(size_t)k * 128 + col];
        int byteoff = col * 768 + ((k * 2) ^ ((col & 7) << 4));
        *(_Float16*)((char*)w1t + byteoff) = (_Float16)v;
    } else {
        int j = i - 384 * 128;
        int col = j >> 7;
        int k = j & 127;
        w2t[j] = (_Float16)w2[(size_t)k * 128 + col];
    }
}

__global__ __launch_bounds__(512, 2) void edge_mlp(
    const float* __restrict__ node_attr,
    const int* __restrict__ eidx,
    const float* __restrict__ edge_attr,
    const _Float16* __restrict__ w1t,   // swizzled, 96KB
    const float* __restrict__ b1,
    const _Float16* __restrict__ w2t,   // linear [col][k], 32KB
    const float* __restrict__ b2,
    float* __restrict__ out) {
    extern __shared__ char lds[];   // [0,96K): w1t_swz  [96K + wid*8K): h per wave

    const int tid = threadIdx.x;
    const int wid = tid >> 6;
    const int lane = tid & 63;
    const int r31 = lane & 31;
    const int g2 = lane >> 5;

    // ---- stage w1t_swz -> LDS, linear cooperative copy (once per block) ----
    {
        const char* src = (const char*)w1t;
        #pragma unroll
        for (int i = 0; i < 12; i++) {
            int off = (tid + i * 512) * 16;   // 512 thr * 12 * 16B = 96KB
            *(f16x8*)(lds + off) = *(const f16x8*)(src + off);
        }
    }

    const int ebase = blockIdx.x * 256 + wid * 32;
    const int e = ebase + r31;
    const int snd = eidx[e];
    const int rcv = eidx[NE + e];
    const float* baseS = node_attr + (size_t)snd * DD;
    const float* baseR = node_attr + (size_t)rcv * DD;
    const float* baseE = edge_attr + (size_t)e * DD;

    float b1v[4], b2v[4];
    #pragma unroll
    for (int n = 0; n < 4; n++) { b1v[n] = b1[n * 32 + r31]; b2v[n] = b2[n * 32 + r31]; }

    __syncthreads();

    // ---------------- GEMM1: [32 x 384] @ [384 x 128] ----------------
    f32x16 acc[4] = {};
    f32x4v abuf[2][16];   // segment double-buffer: 8 k-steps x (lo,hi)

    #pragma unroll
    for (int t = 0; t < 8; t++) {
        const float* p = baseS + t * 16 + g2 * 8;
        abuf[0][2 * t] = *(const f32x4v*)p;
        abuf[0][2 * t + 1] = *(const f32x4v*)(p + 4);
    }

    #pragma unroll
    for (int seg = 0; seg < 3; seg++) {
        if (seg < 2) {
            const float* nxt = (seg == 0) ? baseR : baseE;
            #pragma unroll
            for (int t = 0; t < 8; t++) {
                const float* p = nxt + t * 16 + g2 * 8;
                abuf[(seg + 1) & 1][2 * t] = *(const f32x4v*)p;
                abuf[(seg + 1) & 1][2 * t + 1] = *(const f32x4v*)(p + 4);
            }
        }
        #pragma unroll
        for (int t = 0; t < 8; t++) {
            const int kk = seg * 8 + t;
            f16x8 a = cvt8(abuf[seg & 1][2 * t], abuf[seg & 1][2 * t + 1]);
            const int kb = kk * 32 + g2 * 16;   // byte offset of k-slice
            #pragma unroll
            for (int n = 0; n < 4; n++) {
                const int col = n * 32 + r31;
                f16x8 b = *(const f16x8*)(lds + col * 768 + (kb ^ ((col & 7) << 4)));
                acc[n] = __builtin_amdgcn_mfma_f32_32x32x16_f16(a, b, acc[n], 0, 0, 0);
            }
        }
    }

    // ---- prefetch GEMM2 B fragments (w2t, L2-hot) into regs ----
    f16x8 b2f[8][4];
    #pragma unroll
    for (int kk = 0; kk < 8; kk++) {
        #pragma unroll
        for (int n = 0; n < 4; n++) {
            b2f[kk][n] = *(const f16x8*)(w2t + (size_t)(n * 32 + r31) * 128 + kk * 16 + g2 * 8);
        }
    }

    // ---- bias + relu, h -> LDS (fp16, XOR swizzle) ----
    char* hw = lds + 96 * 1024 + wid * 8192;
    #pragma unroll
    for (int n = 0; n < 4; n++) {
        const int col = n * 32 + r31;
        #pragma unroll
        for (int reg = 0; reg < 16; reg++) {
            const int row = (reg & 3) + 8 * (reg >> 2) + 4 * g2;
            float v = fmaxf(acc[n][reg] + b1v[n], 0.0f);
            const int byteoff = row * 256 + ((col * 2) ^ ((row & 7) << 4));
            *(_Float16*)(hw + byteoff) = (_Float16)v;
        }
    }

    // ---------------- GEMM2: [32 x 128] @ [128 x 128] ----------------
    f32x16 acc2[4] = {};
    #pragma unroll
    for (int kk = 0; kk < 8; kk++) {
        const int kb = kk * 32 + g2 * 16;
        f16x8 a = *(const f16x8*)(hw + r31 * 256 + (kb ^ ((r31 & 7) << 4)));
        #pragma unroll
        for (int n = 0; n < 4; n++) {
            acc2[n] = __builtin_amdgcn_mfma_f32_32x32x16_f16(a, b2f[kk][n], acc2[n], 0, 0, 0);
        }
    }

    // ---- bias + store fp32 ----
    #pragma unroll
    for (int n = 0; n < 4; n++) {
        #pragma unroll
        for (int reg = 0; reg < 16; reg++) {
            const int row = (reg & 3) + 8 * (reg >> 2) + 4 * g2;
            out[(size_t)(ebase + row) * DD + n * 32 + r31] = acc2[n][reg] + b2v[n];
        }
    }
}

extern "C" void kernel_launch(void* const* d_in, const int* in_sizes, int n_in,
                              void* d_out, int out_size, void* d_ws, size_t ws_size,
                              hipStream_t stream) {
    const float* node_attr = (const float*)d_in[0];
    const int* eidx = (const int*)d_in[1];
    const float* edge_attr = (const float*)d_in[2];
    const float* w1 = (const float*)d_in[3];
    const float* b1 = (const float*)d_in[4];
    const float* w2 = (const float*)d_in[5];
    const float* b2 = (const float*)d_in[6];
    float* out = (float*)d_out;

    _Float16* w1t = (_Float16*)d_ws;            // 96KB swizzled
    _Float16* w2t = w1t + 384 * 128;            // 32KB linear

    static bool attr_set = false;
    if (!attr_set) {
        hipFuncSetAttribute((const void*)edge_mlp,
                            hipFuncAttributeMaxDynamicSharedMemorySize, 160 * 1024);
        attr_set = true;
    }

    prep_w<<<256, 256, 0, stream>>>(w1, w2, w1t, w2t);
    edge_mlp<<<3125, 512, 160 * 1024, stream>>>(node_attr, eidx, edge_attr,
                                                w1t, b1, w2t, b2, out);
}